// Round 6
// baseline (596.625 us; speedup 1.0000x reference)
//
#include <hip/hip_runtime.h>

#define N_NODES 100000
#define N_EDGES 1600000
#define F 128

#define SCAN_B 1024
#define SCAN_NB ((N_NODES + SCAN_B - 1) / SCAN_B)   // 98

typedef short bf16x8 __attribute__((ext_vector_type(8)));
typedef float f32x4  __attribute__((ext_vector_type(4)));

union ABFrag {
    bf16x8 v;
    unsigned short u[8];
    uint4  q;
};

__device__ __forceinline__ unsigned short f2bf(float f) {
    unsigned int u = __float_as_uint(f);
    u += 0x7fffu + ((u >> 16) & 1u);   // RNE
    return (unsigned short)(u >> 16);
}
__device__ __forceinline__ float bf2f(unsigned int s) {
    return __uint_as_float(s << 16);
}

// ---------------- CSR build ----------------

__global__ void edge_histogram(const int* __restrict__ erow, int* __restrict__ counts) {
    const int e = blockIdx.x * blockDim.x + threadIdx.x;
    atomicAdd(&counts[erow[e]], 1);
}

__global__ void scan_block_sums(const int* __restrict__ counts, int* __restrict__ bsums) {
    __shared__ int s[SCAN_B];
    const int t = threadIdx.x;
    const int idx = blockIdx.x * SCAN_B + t;
    int v = (idx < N_NODES) ? counts[idx] : 0;
    s[t] = v;
    __syncthreads();
    for (int off = SCAN_B / 2; off > 0; off >>= 1) {
        if (t < off) s[t] += s[t + off];
        __syncthreads();
    }
    if (t == 0) bsums[blockIdx.x] = s[0];
}

__global__ void scan_bsums(const int* __restrict__ bsums, int* __restrict__ boffs) {
    __shared__ int s[128];
    const int t = threadIdx.x;
    int v = (t < SCAN_NB) ? bsums[t] : 0;
    s[t] = v;
    __syncthreads();
    for (int off = 1; off < 128; off <<= 1) {
        int u = (t >= off) ? s[t - off] : 0;
        __syncthreads();
        s[t] += u;
        __syncthreads();
    }
    if (t < SCAN_NB) boffs[t] = s[t] - v;
}

__global__ void scan_final(const int* __restrict__ counts, const int* __restrict__ boffs,
                           int* __restrict__ row_ptr) {
    __shared__ int s[SCAN_B];
    const int t = threadIdx.x;
    const int idx = blockIdx.x * SCAN_B + t;
    int v = (idx < N_NODES) ? counts[idx] : 0;
    s[t] = v;
    __syncthreads();
    for (int off = 1; off < SCAN_B; off <<= 1) {
        int u = (t >= off) ? s[t - off] : 0;
        __syncthreads();
        s[t] += u;
        __syncthreads();
    }
    if (idx < N_NODES) row_ptr[idx] = boffs[blockIdx.x] + s[t] - v;
    if (idx == 0) row_ptr[N_NODES] = N_EDGES;
}

// One 4 B packed store per edge: (col << 15) | bf16(weight) [sign bit is 0].
__global__ void csr_fill(const int* __restrict__ erow, const int* __restrict__ ecol,
                         const float* __restrict__ ewgt,
                         const int* __restrict__ row_ptr, int* __restrict__ cursor,
                         unsigned int* __restrict__ pairs) {
    const int e = blockIdx.x * blockDim.x + threadIdx.x;
    const int dst = erow[e];
    const int pos = atomicAdd(&cursor[dst], 1);
    pairs[row_ptr[dst] + pos] = ((unsigned int)ecol[e] << 15) | (unsigned int)f2bf(ewgt[e]);
}

// ---------------- small converters ----------------

__global__ void transpose_w_bf16(const float* __restrict__ W, unsigned short* __restrict__ Wt) {
    const int i = blockIdx.x * 256 + threadIdx.x;   // 0..16383
    const int n = i >> 7;
    const int k = i & 127;
    Wt[i] = f2bf(W[k * F + n]);                     // Wt[n][k] = W[k][n]
}

__global__ void convert_f32_bf16(const float* __restrict__ X, unsigned short* __restrict__ Y) {
    const int i = blockIdx.x * 256 + threadIdx.x;   // float4 group
    const float4 v = ((const float4*)X)[i];
    ushort4 o;
    o.x = f2bf(v.x); o.y = f2bf(v.y); o.z = f2bf(v.z); o.w = f2bf(v.w);
    ((ushort4*)Y)[i] = o;
}

// ---------------- Fused SpMM + GEMM ----------------
// relu(A(XW)) == relu((AX)W). Block = 256 thr = 4 waves, owns 32 rows.
// Phase 0: each wave prefetches its 8 B-frags of W^T from global (L2-resident;
//          loads are in flight during the gather phase).
// Phase 1: 8 half-waves gather 4 rows each of Z = A@X (fp32 acc, bf16 to LDS).
// Phase 2: MFMA 32x128 x 128x128; wave w owns col-tiles {2w,2w+1} x row-tiles {0,1}.
// Phase 3: relu epilogue; bf16 store (layers 1,2) or fp32 store (layer 3).
__global__ __launch_bounds__(256) void spmm_gemm_fused(
    const unsigned short* __restrict__ Xb,   // bf16 gather source [N][128]
    const int* __restrict__ row_ptr,
    const unsigned int* __restrict__ pairs,  // packed (col<<15)|bf16w
    const unsigned short* __restrict__ Wt,   // bf16 W^T [128][128] (n,k)
    unsigned short* __restrict__ Yb,
    float* __restrict__ Yf,
    int final_mode) {
    __shared__ unsigned short Zs[32][F + 8];   // pad 8 shorts: stride 272 B, 16B-aligned

    const int tid  = threadIdx.x;
    const int wave = tid >> 6;
    const int lane = tid & 63;
    const int base = blockIdx.x * 32;          // grid = 3125 exact

    // Phase 0: prefetch B-frags. B[n = nt*16 + (lane&15)][k = kt*32 + (lane>>4)*8 ..+8]
    const int kq = (lane >> 4) * 8;
    const int n0 = wave * 32 + (lane & 15);
    uint4 bfr[2][4];
#pragma unroll
    for (int kt = 0; kt < 4; ++kt) {
        bfr[0][kt] = *(const uint4*)(Wt + (size_t)n0 * F + kt * 32 + kq);
        bfr[1][kt] = *(const uint4*)(Wt + (size_t)(n0 + 16) * F + kt * 32 + kq);
    }

    // Phase 1: gather
    const int h      = tid >> 5;   // half-wave 0..7
    const int lane32 = tid & 31;
#pragma unroll
    for (int r4 = 0; r4 < 4; ++r4) {
        const int row = base + h * 4 + r4;
        const int beg = row_ptr[row];
        const int end = row_ptr[row + 1];
        float4 a0 = {0.f, 0.f, 0.f, 0.f}, a1 = {0.f, 0.f, 0.f, 0.f};
        int i = beg;
        for (; i + 1 < end; i += 2) {
            const unsigned int p0 = pairs[i], p1 = pairs[i + 1];
            const ushort4 v0 = ((const ushort4*)(Xb + (size_t)(p0 >> 15) * F))[lane32];
            const ushort4 v1 = ((const ushort4*)(Xb + (size_t)(p1 >> 15) * F))[lane32];
            const float w0 = bf2f(p0 & 0x7FFFu);
            const float w1 = bf2f(p1 & 0x7FFFu);
            a0.x += w0 * bf2f(v0.x); a0.y += w0 * bf2f(v0.y);
            a0.z += w0 * bf2f(v0.z); a0.w += w0 * bf2f(v0.w);
            a1.x += w1 * bf2f(v1.x); a1.y += w1 * bf2f(v1.y);
            a1.z += w1 * bf2f(v1.z); a1.w += w1 * bf2f(v1.w);
        }
        if (i < end) {
            const unsigned int p0 = pairs[i];
            const ushort4 v0 = ((const ushort4*)(Xb + (size_t)(p0 >> 15) * F))[lane32];
            const float w0 = bf2f(p0 & 0x7FFFu);
            a0.x += w0 * bf2f(v0.x); a0.y += w0 * bf2f(v0.y);
            a0.z += w0 * bf2f(v0.z); a0.w += w0 * bf2f(v0.w);
        }
        ushort4 z;
        z.x = f2bf(a0.x + a1.x); z.y = f2bf(a0.y + a1.y);
        z.z = f2bf(a0.z + a1.z); z.w = f2bf(a0.w + a1.w);
        *(ushort4*)(&Zs[h * 4 + r4][lane32 * 4]) = z;
    }
    __syncthreads();

    // Phase 2: MFMA. A[m = lane&15][k = kt*32 + kq ..+8] from Zs.
    f32x4 acc[2][2] = {};
#pragma unroll
    for (int kt = 0; kt < 4; ++kt) {
        ABFrag a0f, a1f, b0f, b1f;
        a0f.q = *(const uint4*)(&Zs[lane & 15][kt * 32 + kq]);
        a1f.q = *(const uint4*)(&Zs[16 + (lane & 15)][kt * 32 + kq]);
        b0f.q = bfr[0][kt];
        b1f.q = bfr[1][kt];
        acc[0][0] = __builtin_amdgcn_mfma_f32_16x16x32_bf16(a0f.v, b0f.v, acc[0][0], 0, 0, 0);
        acc[0][1] = __builtin_amdgcn_mfma_f32_16x16x32_bf16(a0f.v, b1f.v, acc[0][1], 0, 0, 0);
        acc[1][0] = __builtin_amdgcn_mfma_f32_16x16x32_bf16(a1f.v, b0f.v, acc[1][0], 0, 0, 0);
        acc[1][1] = __builtin_amdgcn_mfma_f32_16x16x32_bf16(a1f.v, b1f.v, acc[1][1], 0, 0, 0);
    }

    // Phase 3: epilogue. D[row = rt*16 + (lane>>4)*4 + r][col = (wave*2+ct)*16 + (lane&15)]
#pragma unroll
    for (int rt = 0; rt < 2; ++rt) {
#pragma unroll
        for (int ct = 0; ct < 2; ++ct) {
            const int col = (wave * 2 + ct) * 16 + (lane & 15);
#pragma unroll
            for (int r = 0; r < 4; ++r) {
                const int row = base + rt * 16 + (lane >> 4) * 4 + r;
                float v = fmaxf(acc[rt][ct][r], 0.0f);
                if (final_mode) Yf[(size_t)row * F + col] = v;
                else            Yb[(size_t)row * F + col] = f2bf(v);
            }
        }
    }
}

// ---------------- launch ----------------

extern "C" void kernel_launch(void* const* d_in, const int* in_sizes, int n_in,
                              void* d_out, int out_size, void* d_ws, size_t ws_size,
                              hipStream_t stream) {
    const float* x    = (const float*)d_in[0];
    const int*   erow = (const int*)d_in[1];
    const int*   ecol = (const int*)d_in[2];
    const float* ew   = (const float*)d_in[3];
    const float* w1   = (const float*)d_in[4];
    const float* w2   = (const float*)d_in[5];
    const float* w3   = (const float*)d_in[6];
    float* out = (float*)d_out;

    char* ws = (char*)d_ws;
    size_t off = 0;
    auto alloc = [&](size_t bytes) -> char* {
        char* p = ws + off;
        off += (bytes + 255) & ~(size_t)255;
        return p;
    };
    unsigned short* xb   = (unsigned short*)alloc((size_t)N_NODES * F * 2); // 25.6 MB
    unsigned short* bufA = (unsigned short*)alloc((size_t)N_NODES * F * 2); // 25.6 MB
    unsigned short* bufB = (unsigned short*)alloc((size_t)N_NODES * F * 2); // 25.6 MB
    unsigned int* pairs  = (unsigned int*)alloc((size_t)N_EDGES * 4);       // 6.4 MB
    int* counts  = (int*)alloc((size_t)N_NODES * sizeof(int));
    int* row_ptr = (int*)alloc(((size_t)N_NODES + 1) * sizeof(int));
    int* bsums   = (int*)alloc((size_t)SCAN_NB * sizeof(int));
    int* boffs   = (int*)alloc((size_t)SCAN_NB * sizeof(int));
    unsigned short* wt1 = (unsigned short*)alloc((size_t)F * F * 2);
    unsigned short* wt2 = (unsigned short*)alloc((size_t)F * F * 2);
    unsigned short* wt3 = (unsigned short*)alloc((size_t)F * F * 2);

    // --- CSR build (once; reused by all 3 layers) ---
    hipMemsetAsync(counts, 0, (size_t)N_NODES * sizeof(int), stream);
    edge_histogram<<<N_EDGES / 256, 256, 0, stream>>>(erow, counts);
    scan_block_sums<<<SCAN_NB, SCAN_B, 0, stream>>>(counts, bsums);
    scan_bsums<<<1, 128, 0, stream>>>(bsums, boffs);
    scan_final<<<SCAN_NB, SCAN_B, 0, stream>>>(counts, boffs, row_ptr);
    hipMemsetAsync(counts, 0, (size_t)N_NODES * sizeof(int), stream);
    csr_fill<<<N_EDGES / 256, 256, 0, stream>>>(erow, ecol, ew, row_ptr, counts, pairs);

    // --- converts ---
    convert_f32_bf16<<<(N_NODES * F / 4) / 256, 256, 0, stream>>>(x, xb);
    transpose_w_bf16<<<64, 256, 0, stream>>>(w1, wt1);
    transpose_w_bf16<<<64, 256, 0, stream>>>(w2, wt2);
    transpose_w_bf16<<<64, 256, 0, stream>>>(w3, wt3);

    const int fgrid = N_NODES / 32;   // 3125 exact

    // Layer 1: bufA = relu((A @ xb) @ w1)
    spmm_gemm_fused<<<fgrid, 256, 0, stream>>>(xb, row_ptr, pairs, wt1, bufA, nullptr, 0);
    // Layer 2: bufB = relu((A @ bufA) @ w2)
    spmm_gemm_fused<<<fgrid, 256, 0, stream>>>(bufA, row_ptr, pairs, wt2, bufB, nullptr, 0);
    // Layer 3: out = relu((A @ bufB) @ w3)  (fp32)
    spmm_gemm_fused<<<fgrid, 256, 0, stream>>>(bufB, row_ptr, pairs, wt3, nullptr, out, 1);
}

// Round 7
// 506.265 us; speedup vs baseline: 1.1785x; 1.1785x over previous
//
#include <hip/hip_runtime.h>

#define N_NODES 100000
#define N_EDGES 1600000
#define F 128

#define SCAN_B 1024
#define SCAN_NB ((N_NODES + SCAN_B - 1) / SCAN_B)   // 98

typedef short bf16x8 __attribute__((ext_vector_type(8)));
typedef float f32x4  __attribute__((ext_vector_type(4)));

union ABFrag {
    bf16x8 v;
    unsigned short u[8];
    uint4  q;
};

__device__ __forceinline__ unsigned short f2bf(float f) {
    unsigned int u = __float_as_uint(f);
    u += 0x7fffu + ((u >> 16) & 1u);   // RNE
    return (unsigned short)(u >> 16);
}
__device__ __forceinline__ float bflo(unsigned int u) {   // low short -> f32
    return __uint_as_float(u << 16);
}
__device__ __forceinline__ float bfhi(unsigned int u) {   // high short -> f32
    return __uint_as_float(u & 0xFFFF0000u);
}

// ---------------- CSR build ----------------

__global__ void edge_histogram(const int* __restrict__ erow, int* __restrict__ counts) {
    const int e = blockIdx.x * blockDim.x + threadIdx.x;
    atomicAdd(&counts[erow[e]], 1);
}

__global__ void scan_block_sums(const int* __restrict__ counts, int* __restrict__ bsums) {
    __shared__ int s[SCAN_B];
    const int t = threadIdx.x;
    const int idx = blockIdx.x * SCAN_B + t;
    int v = (idx < N_NODES) ? counts[idx] : 0;
    s[t] = v;
    __syncthreads();
    for (int off = SCAN_B / 2; off > 0; off >>= 1) {
        if (t < off) s[t] += s[t + off];
        __syncthreads();
    }
    if (t == 0) bsums[blockIdx.x] = s[0];
}

__global__ void scan_bsums(const int* __restrict__ bsums, int* __restrict__ boffs) {
    __shared__ int s[128];
    const int t = threadIdx.x;
    int v = (t < SCAN_NB) ? bsums[t] : 0;
    s[t] = v;
    __syncthreads();
    for (int off = 1; off < 128; off <<= 1) {
        int u = (t >= off) ? s[t - off] : 0;
        __syncthreads();
        s[t] += u;
        __syncthreads();
    }
    if (t < SCAN_NB) boffs[t] = s[t] - v;
}

__global__ void scan_final(const int* __restrict__ counts, const int* __restrict__ boffs,
                           int* __restrict__ row_ptr) {
    __shared__ int s[SCAN_B];
    const int t = threadIdx.x;
    const int idx = blockIdx.x * SCAN_B + t;
    int v = (idx < N_NODES) ? counts[idx] : 0;
    s[t] = v;
    __syncthreads();
    for (int off = 1; off < SCAN_B; off <<= 1) {
        int u = (t >= off) ? s[t - off] : 0;
        __syncthreads();
        s[t] += u;
        __syncthreads();
    }
    if (idx < N_NODES) row_ptr[idx] = boffs[blockIdx.x] + s[t] - v;
    if (idx == 0) row_ptr[N_NODES] = N_EDGES;
}

// One 4 B packed store per edge: (col << 15) | bf16(weight) [weight sign is 0].
__global__ void csr_fill(const int* __restrict__ erow, const int* __restrict__ ecol,
                         const float* __restrict__ ewgt,
                         const int* __restrict__ row_ptr, int* __restrict__ cursor,
                         unsigned int* __restrict__ pairs) {
    const int e = blockIdx.x * blockDim.x + threadIdx.x;
    const int dst = erow[e];
    const int pos = atomicAdd(&cursor[dst], 1);
    pairs[row_ptr[dst] + pos] = ((unsigned int)ecol[e] << 15) | (unsigned int)f2bf(ewgt[e]);
}

// ---------------- W^T -> bf16 (once per weight) ----------------
__global__ void transpose_w_bf16(const float* __restrict__ W, unsigned short* __restrict__ Wt) {
    const int i = blockIdx.x * 256 + threadIdx.x;   // 0..16383
    const int n = i >> 7;
    const int k = i & 127;
    Wt[i] = f2bf(W[k * F + n]);                     // Wt[n][k] = W[k][n]
}

// ---------------- MFMA bf16 GEMM (R4 structure, proven) ----------------
__global__ __launch_bounds__(256) void gemm_mfma(
    const float* __restrict__ Xf,            // fp32 input (layer 1) or null
    const unsigned short* __restrict__ Xb,   // bf16 input (layers 2/3) or null
    const unsigned short* __restrict__ Wt,   // bf16 W^T [128][128]
    unsigned short* __restrict__ Y,          // bf16 out [N][128]
    int use_f32_in)                          // 1: Xf no relu; 0: Xb with relu
{
    __shared__ unsigned short Wl[4 * 8 * 64 * 8];   // 32 KB, frag order

    const int tid  = threadIdx.x;
    const int wave = tid >> 6;
    const int lane = tid & 63;

    for (int s = tid; s < 2048; s += 256) {
        const int ln  = s & 63;
        const int ntk = s >> 6;           // kt*8 + nt
        const int nt  = ntk & 7;
        const int kt  = ntk >> 3;
        const int n   = nt * 16 + (ln & 15);
        const int k   = kt * 32 + (ln >> 4) * 8;
        *(uint4*)(&Wl[s * 8]) = *(const uint4*)(Wt + n * F + k);
    }
    __syncthreads();

    const int m     = blockIdx.x * 64 + wave * 16 + (lane & 15);
    const bool mval = (m < N_NODES);
    const int kq    = (lane >> 4) * 8;

    f32x4 acc[8] = {};

#pragma unroll
    for (int kt = 0; kt < 4; ++kt) {
        ABFrag a;
        if (mval) {
            if (use_f32_in) {
                const float* p = Xf + (size_t)m * F + kt * 32 + kq;
                const float4 u0 = *(const float4*)p;
                const float4 u1 = *(const float4*)(p + 4);
                a.u[0] = f2bf(u0.x); a.u[1] = f2bf(u0.y);
                a.u[2] = f2bf(u0.z); a.u[3] = f2bf(u0.w);
                a.u[4] = f2bf(u1.x); a.u[5] = f2bf(u1.y);
                a.u[6] = f2bf(u1.z); a.u[7] = f2bf(u1.w);
            } else {
                a.q = *(const uint4*)(Xb + (size_t)m * F + kt * 32 + kq);
#pragma unroll
                for (int j = 0; j < 8; ++j)
                    if (a.u[j] & 0x8000u) a.u[j] = 0;   // relu on bf16 bits
            }
        } else {
            a.q = make_uint4(0, 0, 0, 0);
        }
#pragma unroll
        for (int nt = 0; nt < 8; ++nt) {
            ABFrag b;
            b.q = *(const uint4*)(&Wl[((kt * 8 + nt) * 64 + lane) * 8]);
            acc[nt] = __builtin_amdgcn_mfma_f32_16x16x32_bf16(a.v, b.v, acc[nt], 0, 0, 0);
        }
    }

    const int rbase = blockIdx.x * 64 + wave * 16 + (lane >> 4) * 4;
    const int cbase = lane & 15;
#pragma unroll
    for (int r = 0; r < 4; ++r) {
        const int row = rbase + r;
        if (row < N_NODES) {
#pragma unroll
            for (int nt = 0; nt < 8; ++nt) {
                Y[(size_t)row * F + nt * 16 + cbase] = f2bf(acc[nt][r]);
            }
        }
    }
}

// ---------------- CSR SpMM: quarter-wave per row ----------------
// 16 lanes per row, lane covers 8 bf16 cols (uint4 = 16 B load). One wave64
// vmem instruction gathers 4 edges' rows (1 KB). Edges unrolled x2 for ILP.
// Block 256 = 16 rows; grid = N_NODES/16 exact.
__global__ __launch_bounds__(256) void spmm_csr_bf16(
    const unsigned short* __restrict__ Xb,
    const int* __restrict__ row_ptr,
    const unsigned int* __restrict__ pairs,
    unsigned short* __restrict__ Ob,
    float* __restrict__ Of,
    int final_mode) {
    const int tid = threadIdx.x;
    const int l16 = tid & 15;            // lane within quarter-wave
    const int q   = tid >> 4;            // quarter index 0..15
    const int row = blockIdx.x * 16 + q;

    const int beg = row_ptr[row];
    const int end = row_ptr[row + 1];

    float a[8] = {};
    int i = beg;
    for (; i + 1 < end; i += 2) {
        const unsigned int p0 = pairs[i], p1 = pairs[i + 1];
        const uint4 v0 = *(const uint4*)(Xb + (size_t)(p0 >> 15) * F + l16 * 8);
        const uint4 v1 = *(const uint4*)(Xb + (size_t)(p1 >> 15) * F + l16 * 8);
        const float w0 = bflo(p0 & 0x7FFFu);
        const float w1 = bflo(p1 & 0x7FFFu);
        a[0] += w0 * bflo(v0.x); a[1] += w0 * bfhi(v0.x);
        a[2] += w0 * bflo(v0.y); a[3] += w0 * bfhi(v0.y);
        a[4] += w0 * bflo(v0.z); a[5] += w0 * bfhi(v0.z);
        a[6] += w0 * bflo(v0.w); a[7] += w0 * bfhi(v0.w);
        a[0] += w1 * bflo(v1.x); a[1] += w1 * bfhi(v1.x);
        a[2] += w1 * bflo(v1.y); a[3] += w1 * bfhi(v1.y);
        a[4] += w1 * bflo(v1.z); a[5] += w1 * bfhi(v1.z);
        a[6] += w1 * bflo(v1.w); a[7] += w1 * bfhi(v1.w);
    }
    if (i < end) {
        const unsigned int p0 = pairs[i];
        const uint4 v0 = *(const uint4*)(Xb + (size_t)(p0 >> 15) * F + l16 * 8);
        const float w0 = bflo(p0 & 0x7FFFu);
        a[0] += w0 * bflo(v0.x); a[1] += w0 * bfhi(v0.x);
        a[2] += w0 * bflo(v0.y); a[3] += w0 * bfhi(v0.y);
        a[4] += w0 * bflo(v0.z); a[5] += w0 * bfhi(v0.z);
        a[6] += w0 * bflo(v0.w); a[7] += w0 * bfhi(v0.w);
    }

    if (final_mode) {
        float4 o0 = {fmaxf(a[0], 0.f), fmaxf(a[1], 0.f), fmaxf(a[2], 0.f), fmaxf(a[3], 0.f)};
        float4 o1 = {fmaxf(a[4], 0.f), fmaxf(a[5], 0.f), fmaxf(a[6], 0.f), fmaxf(a[7], 0.f)};
        float* p = Of + (size_t)row * F + l16 * 8;
        *(float4*)p = o0;
        *(float4*)(p + 4) = o1;
    } else {
        // store raw bf16 (relu applied by consumer gemm's A-load)
        uint4 o;
        o.x = (unsigned int)f2bf(a[0]) | ((unsigned int)f2bf(a[1]) << 16);
        o.y = (unsigned int)f2bf(a[2]) | ((unsigned int)f2bf(a[3]) << 16);
        o.z = (unsigned int)f2bf(a[4]) | ((unsigned int)f2bf(a[5]) << 16);
        o.w = (unsigned int)f2bf(a[6]) | ((unsigned int)f2bf(a[7]) << 16);
        *(uint4*)(Ob + (size_t)row * F + l16 * 8) = o;
    }
}

// ---------------- launch ----------------

extern "C" void kernel_launch(void* const* d_in, const int* in_sizes, int n_in,
                              void* d_out, int out_size, void* d_ws, size_t ws_size,
                              hipStream_t stream) {
    const float* x    = (const float*)d_in[0];
    const int*   erow = (const int*)d_in[1];
    const int*   ecol = (const int*)d_in[2];
    const float* ew   = (const float*)d_in[3];
    const float* w1   = (const float*)d_in[4];
    const float* w2   = (const float*)d_in[5];
    const float* w3   = (const float*)d_in[6];
    float* out = (float*)d_out;

    char* ws = (char*)d_ws;
    size_t off = 0;
    auto alloc = [&](size_t bytes) -> char* {
        char* p = ws + off;
        off += (bytes + 255) & ~(size_t)255;
        return p;
    };
    unsigned short* bufA = (unsigned short*)alloc((size_t)N_NODES * F * 2); // 25.6 MB
    unsigned short* bufB = (unsigned short*)alloc((size_t)N_NODES * F * 2); // 25.6 MB
    unsigned int* pairs  = (unsigned int*)alloc((size_t)N_EDGES * 4);       // 6.4 MB
    int* counts  = (int*)alloc((size_t)N_NODES * sizeof(int));
    int* row_ptr = (int*)alloc(((size_t)N_NODES + 1) * sizeof(int));
    int* bsums   = (int*)alloc((size_t)SCAN_NB * sizeof(int));
    int* boffs   = (int*)alloc((size_t)SCAN_NB * sizeof(int));
    unsigned short* wt1 = (unsigned short*)alloc((size_t)F * F * 2);
    unsigned short* wt2 = (unsigned short*)alloc((size_t)F * F * 2);
    unsigned short* wt3 = (unsigned short*)alloc((size_t)F * F * 2);

    // --- CSR build (once; reused by all 3 layers) ---
    hipMemsetAsync(counts, 0, (size_t)N_NODES * sizeof(int), stream);
    edge_histogram<<<N_EDGES / 256, 256, 0, stream>>>(erow, counts);
    scan_block_sums<<<SCAN_NB, SCAN_B, 0, stream>>>(counts, bsums);
    scan_bsums<<<1, 128, 0, stream>>>(bsums, boffs);
    scan_final<<<SCAN_NB, SCAN_B, 0, stream>>>(counts, boffs, row_ptr);
    hipMemsetAsync(counts, 0, (size_t)N_NODES * sizeof(int), stream);
    csr_fill<<<N_EDGES / 256, 256, 0, stream>>>(erow, ecol, ew, row_ptr, counts, pairs);

    // --- Weight transposes to bf16 ---
    transpose_w_bf16<<<64, 256, 0, stream>>>(w1, wt1);
    transpose_w_bf16<<<64, 256, 0, stream>>>(w2, wt2);
    transpose_w_bf16<<<64, 256, 0, stream>>>(w3, wt3);

    const int ggrid = (N_NODES + 63) / 64;   // 1563
    const int sgrid = N_NODES / 16;          // 6250 exact

    // Layer 1
    gemm_mfma<<<ggrid, 256, 0, stream>>>(x, nullptr, wt1, bufA, 1);
    spmm_csr_bf16<<<sgrid, 256, 0, stream>>>(bufA, row_ptr, pairs, bufB, nullptr, 0);
    // Layer 2
    gemm_mfma<<<ggrid, 256, 0, stream>>>(nullptr, bufB, wt2, bufA, 0);
    spmm_csr_bf16<<<sgrid, 256, 0, stream>>>(bufA, row_ptr, pairs, bufB, nullptr, 0);
    // Layer 3
    gemm_mfma<<<ggrid, 256, 0, stream>>>(nullptr, bufB, wt3, bufA, 0);
    spmm_csr_bf16<<<sgrid, 256, 0, stream>>>(bufA, row_ptr, pairs, nullptr, out, 1);
}